// Round 8
// baseline (30.635 us; speedup 1.0000x reference)
//
#include <hip/hip_runtime.h>
#include <hip/hip_bf16.h>
#include <math.h>

#define TAGS   20
#define TSTART (TAGS - 2)
#define TSTOP  (TAGS - 1)

constexpr float  LOG2E = 1.4426950408889634f;
constexpr float  LN2f  = 0.6931471805599453f;
constexpr double LN2d  = 0.69314718055994530942;

typedef __attribute__((ext_vector_type(8))) short short8;
typedef __attribute__((ext_vector_type(4))) float f32x4;
union U4 { unsigned int u[4]; short8 v; };

// f32x2 -> packed bf16x2, round-half-up (+0x8000 then high halves via one
// v_perm_b32) — validated round 7, absmax 0.0. 3 VALU ops.
__device__ __forceinline__ unsigned int pk2(float lo, float hi) {
    unsigned int a = __float_as_uint(hi) + 0x8000u;
    unsigned int b = __float_as_uint(lo) + 0x8000u;
#if __has_builtin(__builtin_amdgcn_perm)
    return __builtin_amdgcn_perm(a, b, 0x07060302u);   // {a[31:16], b[31:16]}
#else
    return (a & 0xFFFF0000u) | (b >> 16);
#endif
}
#if __has_builtin(__builtin_amdgcn_exp2f)
__device__ __forceinline__ float fexp2(float x) { return __builtin_amdgcn_exp2f(x); }
#else
__device__ __forceinline__ float fexp2(float x) { return exp2f(x); }
#endif
#if __has_builtin(__builtin_amdgcn_logf)
__device__ __forceinline__ float flog2(float x) { return __builtin_amdgcn_logf(x); }
#else
__device__ __forceinline__ float flog2(float x) { return log2f(x); }
#endif
__device__ __forceinline__ float frcp(float x) { return __builtin_amdgcn_rcpf(x); }
__device__ __forceinline__ float bcast(float v, int srclane) {
    return __int_as_float(__builtin_amdgcn_readlane(__float_as_int(v), srclane));
}
// k-slot -> state-row permutation (split-half layout of gfx950 16x16x32),
// applied consistently to A and B; makes C/D per-lane regs == B per-lane
// k-slots (validated end-to-end: rounds 4/5/7 absmax 0.0).
__device__ __forceinline__ int rho(int k) {
    int g = k >> 3, i = k & 7;
    return (i < 4) ? (4 * g + i) : (16 + 4 * g + (i - 4));
}

// ========================== FUSED KERNEL ==================================
// One block = one batch, 16 waves; wave w owns chunk w (32 steps, branchless
// wave-uniform loop). 4-level MFMA tree combines the 16 chunk matrices in
// LDS. Final: v0^T * G_total, LSE, gold score, then deterministic fixed-point
// atomic accumulation into ws (2^20 scale); last block writes d_out.
__global__ __launch_bounds__(1024)
void crf_fused_kernel(const float* __restrict__ feats,
                      const float* __restrict__ Tm,
                      const int*   __restrict__ tags,
                      const int*   __restrict__ lengths,
                      unsigned long long* __restrict__ acc,
                      unsigned int*       __restrict__ cnt,
                      float*              __restrict__ out,
                      int L)
{
    __shared__ float  smem[16 * 1024];   // 64 KB: ef staging; later tree slots (stride 1088)
    __shared__ float  sv[32];
    __shared__ int    EsX[8];
    __shared__ float  gred[16];
    __shared__ double fwd_sh;

    const int b    = blockIdx.x;
    const int tid  = threadIdx.x;
    const int w    = tid >> 6;           // wave id 0..15 == chunk id
    const int lane = tid & 63;
    const int G    = lane >> 4, col = lane & 15;
    const int len  = lengths[b];

    // ---- stage ef = 2^(feat*log2e) for chunk w (32x32, pads 0) ----
    // Wave w only ever reads its own staged chunk -> same-wave DS ordering,
    // NO barrier needed before the chunk loop.
    float* efc = smem + w * 1024;
    const float* fc = feats + ((size_t)b * L + (size_t)w * 32) * TAGS;
    for (int it = lane; it < 160; it += 64) {           // 160 float4 = 640 floats
        float4 v = reinterpret_cast<const float4*>(fc)[it];
        float vv[4] = {v.x, v.y, v.z, v.w};
        #pragma unroll
        for (int u = 0; u < 4; ++u) {
            int f = it * 4 + u;
            int t = f / TAGS, tag = f - t * TAGS;
            efc[t * 32 + tag] = fexp2(vv[u] * LOG2E);
        }
    }
    for (int q = lane; q < 32 * 12; q += 64) {
        int t = q / 12;
        efc[t * 32 + 20 + (q - t * 12)] = 0.f;
    }

    // ---- A fragments from T: A_x[m][k] = 2^(T[16x+m][rho(k)]*log2e) ----
    U4 A0, A1;
    #pragma unroll
    for (int t = 0; t < 4; ++t) {
        int k0 = 8 * G + 2 * t;
        int r0 = rho(k0), r1 = rho(k0 + 1);
        int m1 = 16 + col;
        float a00 = (r0 < TAGS) ? fexp2(Tm[col * TAGS + r0] * LOG2E) : 0.f;
        float a01 = (r1 < TAGS) ? fexp2(Tm[col * TAGS + r1] * LOG2E) : 0.f;
        float a10 = (m1 < TAGS && r0 < TAGS) ? fexp2(Tm[m1 * TAGS + r0] * LOG2E) : 0.f;
        float a11 = (m1 < TAGS && r1 < TAGS) ? fexp2(Tm[m1 * TAGS + r1] * LOG2E) : 0.f;
        A0.u[t] = pk2(a00, a01);
        A1.u[t] = pk2(a10, a11);
    }

    auto strip = [&](f32x4& C00, f32x4& C01, f32x4& C10, f32x4& C11) -> int {
        float pr = C00[0] + C00[1] + C00[2] + C00[3] + C10[0] + C10[1] + C10[2] + C10[3];
        int pb = __builtin_amdgcn_readfirstlane(__float_as_int(pr)); // col0 sample (>0 always)
        int ex = ((pb >> 23) & 0xFF) - 127;
        float s = __uint_as_float((unsigned)(127 - ex) << 23);       // 2^-ex
        #pragma unroll
        for (int j = 0; j < 4; ++j) { C00[j] *= s; C01[j] *= s; C10[j] *= s; C11[j] *= s; }
        return ex;
    };
    auto xwr = [&](int slot, const f32x4& C00, const f32x4& C01,
                   const f32x4& C10, const f32x4& C11, int E) {
        float* Xs = smem + slot * 1088;                 // row-major, stride 34
        #pragma unroll
        for (int j = 0; j < 4; ++j) {
            Xs[(4 * G + j) * 34 + col]           = C00[j];
            Xs[(4 * G + j) * 34 + col + 16]      = C01[j];
            Xs[(16 + 4 * G + j) * 34 + col]      = C10[j];
            Xs[(16 + 4 * G + j) * 34 + col + 16] = C11[j];
        }
        if (lane == 0) EsX[slot] = E;
    };
    auto prod = [&](int slot, f32x4& C00, f32x4& C01, f32x4& C10, f32x4& C11) -> int {
        const float* Xs = smem + slot * 1088;
        U4 Ax0, Ax1;
        #pragma unroll
        for (int t = 0; t < 4; ++t) {
            int r = rho(8 * G + 2 * t);                 // rho(k0), rho(k0+1) adjacent
            float2 x0 = *reinterpret_cast<const float2*>(&Xs[col * 34 + r]);
            float2 x1 = *reinterpret_cast<const float2*>(&Xs[(16 + col) * 34 + r]);
            Ax0.u[t] = pk2(x0.x, x0.y);
            Ax1.u[t] = pk2(x1.x, x1.y);
        }
        U4 B0, B1;
        B0.u[0] = pk2(C00[0], C00[1]);
        B0.u[1] = pk2(C00[2], C00[3]);
        B0.u[2] = pk2(C10[0], C10[1]);
        B0.u[3] = pk2(C10[2], C10[3]);
        B1.u[0] = pk2(C01[0], C01[1]);
        B1.u[1] = pk2(C01[2], C01[3]);
        B1.u[2] = pk2(C11[0], C11[1]);
        B1.u[3] = pk2(C11[2], C11[3]);
        f32x4 z = {0.f, 0.f, 0.f, 0.f};
        f32x4 n00 = __builtin_amdgcn_mfma_f32_16x16x32_bf16(Ax0.v, B0.v, z, 0, 0, 0);
        f32x4 n01 = __builtin_amdgcn_mfma_f32_16x16x32_bf16(Ax0.v, B1.v, z, 0, 0, 0);
        f32x4 n10 = __builtin_amdgcn_mfma_f32_16x16x32_bf16(Ax1.v, B0.v, z, 0, 0, 0);
        f32x4 n11 = __builtin_amdgcn_mfma_f32_16x16x32_bf16(Ax1.v, B1.v, z, 0, 0, 0);
        C00 = n00; C01 = n01; C10 = n10; C11 = n11;
        return strip(C00, C01, C10, C11);
    };

    // ---- chunk product: single chain, branchless wave-uniform bounds ----
    f32x4 C00, C01, C10, C11;
    #pragma unroll
    for (int j = 0; j < 4; ++j) {
        float d = (4 * G + j == col) ? 1.f : 0.f;       // R = I (pad diag harmless)
        C00[j] = d; C11[j] = d; C01[j] = 0.f; C10[j] = 0.f;
    }
    int E = 0;

    const int lo  = (w == 0) ? 1 : w * 32;
    const int hiE = min(w * 32 + 31, len - 1);
    for (int l = hiE; l >= lo; --l) {
        const int t = l - w * 32;
        float4 e0 = *reinterpret_cast<const float4*>(&efc[t * 32 + 4 * G]);
        float4 e1 = *reinterpret_cast<const float4*>(&efc[t * 32 + 16 + 4 * G]);
        U4 B0, B1;
        B0.u[0] = pk2(C00[0] * e0.x, C00[1] * e0.y);
        B0.u[1] = pk2(C00[2] * e0.z, C00[3] * e0.w);
        B0.u[2] = pk2(C10[0] * e1.x, C10[1] * e1.y);
        B0.u[3] = pk2(C10[2] * e1.z, C10[3] * e1.w);
        B1.u[0] = pk2(C01[0] * e0.x, C01[1] * e0.y);
        B1.u[1] = pk2(C01[2] * e0.z, C01[3] * e0.w);
        B1.u[2] = pk2(C11[0] * e1.x, C11[1] * e1.y);
        B1.u[3] = pk2(C11[2] * e1.z, C11[3] * e1.w);
        f32x4 z = {0.f, 0.f, 0.f, 0.f};
        C00 = __builtin_amdgcn_mfma_f32_16x16x32_bf16(A0.v, B0.v, z, 0, 0, 0);
        C01 = __builtin_amdgcn_mfma_f32_16x16x32_bf16(A0.v, B1.v, z, 0, 0, 0);
        C10 = __builtin_amdgcn_mfma_f32_16x16x32_bf16(A1.v, B0.v, z, 0, 0, 0);
        C11 = __builtin_amdgcn_mfma_f32_16x16x32_bf16(A1.v, B1.v, z, 0, 0, 0);
        if ((l & 3) == 0) E += strip(C00, C01, C10, C11);
    }
    __syncthreads();   // all chunks done; smem reused as tree slots

    // ---- 4-level binary tree; node G_{2p}*G_{2p+1} lands on the odd wave ----
    // L1: producers even w -> slot w/2; consumers odd w.
    if ((w & 1) == 0) xwr(w >> 1, C00, C01, C10, C11, E);
    __syncthreads();
    if (w & 1) { int s = (w - 1) >> 1; E += EsX[s] + prod(s, C00, C01, C10, C11); }
    __syncthreads();
    // L2: producers w in {1,5,9,13} -> slot (w-1)/4; consumers {3,7,11,15}.
    if ((w & 3) == 1) xwr((w - 1) >> 2, C00, C01, C10, C11, E);
    __syncthreads();
    if ((w & 3) == 3) { int s = (w - 3) >> 2; E += EsX[s] + prod(s, C00, C01, C10, C11); }
    __syncthreads();
    // L3: producers w in {3,11} -> slot (w-3)/8; consumers {7,15}.
    if ((w & 7) == 3) xwr((w - 3) >> 3, C00, C01, C10, C11, E);
    __syncthreads();
    if ((w & 7) == 7) { int s = (w - 7) >> 3; E += EsX[s] + prod(s, C00, C01, C10, C11); }
    __syncthreads();
    // L4: producer w=7 -> slot 0; consumer w=15 -> G_total.
    if (w == 7) xwr(0, C00, C01, C10, C11, E);
    __syncthreads();
    if (w == 15) {
        E += EsX[0] + prod(0, C00, C01, C10, C11);
        float* Gt = smem;                                // col-major: Gt[n*34 + r]
        #pragma unroll
        for (int j = 0; j < 4; ++j) {
            Gt[col * 34 + 4 * G + j]             = C00[j];
            Gt[col * 34 + 16 + 4 * G + j]        = C10[j];
            Gt[(col + 16) * 34 + 4 * G + j]      = C01[j];
            Gt[(col + 16) * 34 + 16 + 4 * G + j] = C11[j];
        }
        if (lane == 0) EsX[0] = E;
    }
    __syncthreads();

    // ---- final: part^T = v0^T G_total ; LSE with T[:,STOP] (max-subtracted;
    //      the STOP column is -10000 everywhere!) ----
    if (w == 0) {
        const int n2 = lane & 31;
        float p = (n2 < TAGS) ? (feats[(size_t)b * L * TAGS + n2] + Tm[TSTART * TAGS + n2]) * LOG2E
                              : -1e30f;
        float mx = p;
        #pragma unroll
        for (int off = 32; off; off >>= 1) mx = fmaxf(mx, __shfl_xor(mx, off));
        float v = (n2 < TAGS) ? fexp2(p - mx) : 0.f;
        if (lane < 32) sv[lane] = v;                     // same-wave DS ordering
        const float* Gt = smem;
        float vn = 0.f;
        #pragma unroll
        for (int r = 0; r < 32; r += 2) {
            float2 g2 = *reinterpret_cast<const float2*>(&Gt[n2 * 34 + r]);
            vn = fmaf(sv[r], g2.x, vn);
            vn = fmaf(sv[r + 1], g2.y, vn);
        }
        float cstop = Tm[n2 * TAGS + TSTOP];
        float mc = (n2 < TAGS) ? cstop : -INFINITY;
        #pragma unroll
        for (int off = 32; off; off >>= 1) mc = fmaxf(mc, __shfl_xor(mc, off));
        float ts = (lane < 32 && n2 < TAGS) ? vn * fexp2((cstop - mc) * LOG2E) : 0.f;
        #pragma unroll
        for (int off = 32; off; off >>= 1) ts += __shfl_xor(ts, off);
        if (lane == 0)
            fwd_sh = ((double)mx + (double)EsX[0] + (double)flog2(ts)) * LN2d + (double)mc;
    }

    // ---- gold path score (1024 threads, <=1 step each) ----
    float g = 0.f;
    for (int l = tid; l < len; l += 1024) {
        int tt = tags[(size_t)b * L + l];
        int pv = (l == 0) ? TSTART : tags[(size_t)b * L + l - 1];
        g += feats[((size_t)b * L + l) * TAGS + tt] + Tm[pv * TAGS + tt];
    }
    #pragma unroll
    for (int off = 32; off; off >>= 1) g += __shfl_xor(g, off);
    if (lane == 0) gred[w] = g;
    __syncthreads();

    // ---- deterministic fixed-point accumulation (integer atomics are
    //      associative -> bitwise deterministic); last block writes d_out ----
    if (tid == 0) {
        float gs = 0.f;
        #pragma unroll
        for (int i = 0; i < 16; ++i) gs += gred[i];
        double gold = (double)gs + (double)Tm[tags[(size_t)b * L + len - 1] * TAGS + TSTOP];
        double pd   = fwd_sh - gold;
        long long q = (long long)(pd * 1048576.0 + (pd >= 0.0 ? 0.5 : -0.5));  // 2^20 scale
        atomicAdd(acc, (unsigned long long)q);
        __threadfence();
        unsigned int c = atomicAdd(cnt, 1u);
        if (c == gridDim.x - 1) {
            long long tot = (long long)atomicAdd(acc, 0ULL);   // RMW read: coherent
            out[0] = (float)((double)tot * (1.0 / 1048576.0));
        }
    }
}

// ==================== FALLBACK (round-2 serial kernel) ====================
__global__ __launch_bounds__(64)
void crf_fwd_kernel(const float* __restrict__ feats,
                    const float* __restrict__ Tm,
                    const int*   __restrict__ tags,
                    const int*   __restrict__ lengths,
                    double*      __restrict__ partial,
                    int B, int L)
{
    __shared__ float le[512 * TAGS];
    const int b    = blockIdx.x;
    const int lane = threadIdx.x;
    const int j    = (lane < TAGS) ? lane : 0;
    const float* fb  = feats + (size_t)b * L * TAGS;
    const int*   tg  = tags  + (size_t)b * L;
    const int    len = lengths[b];

    const int nv4 = (L * TAGS) >> 2;
    for (int it = lane; it < nv4; it += 64) {
        float4 v = reinterpret_cast<const float4*>(fb)[it];
        float4 e;
        e.x = fexp2(v.x * LOG2E); e.y = fexp2(v.y * LOG2E);
        e.z = fexp2(v.z * LOG2E); e.w = fexp2(v.w * LOG2E);
        reinterpret_cast<float4*>(le)[it] = e;
    }
    __syncthreads();

    float ET[TAGS];
    #pragma unroll
    for (int i = 0; i < TAGS; ++i) ET[i] = fexp2(Tm[i * TAGS + j] * LOG2E);

    float w0   = flog2(le[j]) + Tm[TSTART * TAGS + j] * LOG2E;
    float base = bcast(w0, 0);
    float P    = fexp2(w0 - base);
    float M2   = base;
    float Pa[TAGS];
    #pragma unroll
    for (int i = 0; i < TAGS; ++i) Pa[i] = bcast(P, i);
    const float* leb = le + j;

    auto STEP = [&](int l, float efv, float rsv, bool scaled) {
        float s0 = 0.f, s1 = 0.f, s2 = 0.f, s3 = 0.f;
        #pragma unroll
        for (int i = 0; i < TAGS; i += 4) {
            s0 = fmaf(ET[i + 0], Pa[i + 0], s0);
            s1 = fmaf(ET[i + 1], Pa[i + 1], s1);
            s2 = fmaf(ET[i + 2], Pa[i + 2], s2);
            s3 = fmaf(ET[i + 3], Pa[i + 3], s3);
        }
        float s   = (s0 + s1) + (s2 + s3);
        float cur = s * efv;
        float pn  = (l < len) ? cur : P;
        P = scaled ? pn * rsv : pn;
        #pragma unroll
        for (int i = 0; i < TAGS; ++i) Pa[i] = bcast(P, i);
    };

    float efb[4];
    #pragma unroll
    for (int k = 0; k < 4; ++k) { int ln = 1 + k; ln = (ln < L) ? ln : (L - 1); efb[k] = leb[ln * TAGS]; }

    float rs = 1.0f, lg0 = 0.0f;
    int l0 = 1;
    for (; l0 + 3 < L; l0 += 4) {
        if (l0 >= len) break;
        float efn[4];
        #pragma unroll
        for (int k = 0; k < 4; ++k) { int ln = l0 + 4 + k; ln = (ln < L) ? ln : (L - 1); efn[k] = leb[ln * TAGS]; }
        M2 += lg0;
        STEP(l0 + 0, efb[0], rs, true);
        STEP(l0 + 1, efb[1], 1.f, false);
        STEP(l0 + 2, efb[2], 1.f, false);
        STEP(l0 + 3, efb[3], 1.f, false);
        float p0 = Pa[0];
        rs = frcp(p0); lg0 = flog2(p0);
        #pragma unroll
        for (int k = 0; k < 4; ++k) efb[k] = efn[k];
    }
    if (l0 < len) {
        int rem = L - l0;
        M2 += lg0;
        if (rem > 0) STEP(l0 + 0, efb[0], rs, true);
        if (rem > 1) STEP(l0 + 1, efb[1], 1.f, false);
        if (rem > 2) STEP(l0 + 2, efb[2], 1.f, false);
        if (rem > 3) STEP(l0 + 3, efb[3], 1.f, false);
    }

    float cstop = Tm[j * TAGS + TSTOP];
    float mc = (lane < TAGS) ? cstop : -INFINITY;
    #pragma unroll
    for (int off = 32; off; off >>= 1) mc = fmaxf(mc, __shfl_xor(mc, off));
    float t = (lane < TAGS) ? P * fexp2((cstop - mc) * LOG2E) : 0.f;
    #pragma unroll
    for (int off = 32; off; off >>= 1) t += __shfl_xor(t, off);
    double fwd = ((double)M2 + (double)flog2(t)) * LN2d + (double)mc;

    float g = 0.f;
    for (int l = lane; l < len; l += 64) {
        int tt = tg[l];
        int pv = (l == 0) ? TSTART : tg[l - 1];
        g += flog2(le[l * TAGS + tt]) * LN2f + Tm[pv * TAGS + tt];
    }
    #pragma unroll
    for (int off = 32; off; off >>= 1) g += __shfl_xor(g, off);

    if (lane == 0) {
        double gold = (double)g + (double)Tm[tg[len - 1] * TAGS + TSTOP];
        partial[b] = fwd - gold;
    }
}

__global__ __launch_bounds__(256)
void crf_reduce_kernel(const double* __restrict__ partial, float* __restrict__ out, int B)
{
    __shared__ double sh[256];
    const int t = threadIdx.x;
    double acc = 0.0;
    for (int i = t; i < B; i += 256) acc += partial[i];
    sh[t] = acc;
    __syncthreads();
    for (int s = 128; s; s >>= 1) {
        if (t < s) sh[t] += sh[t + s];
        __syncthreads();
    }
    if (t == 0) out[0] = (float)sh[0];
}

extern "C" void kernel_launch(void* const* d_in, const int* in_sizes, int n_in,
                              void* d_out, int out_size, void* d_ws, size_t ws_size,
                              hipStream_t stream)
{
    const float* feats   = (const float*)d_in[0];
    const float* Tm      = (const float*)d_in[1];
    const int*   tags    = (const int*)d_in[2];
    const int*   lengths = (const int*)d_in[3];

    const int B = in_sizes[3];
    const int L = in_sizes[2] / B;

    if (L == 512 && ws_size >= 64) {
        unsigned long long* acc = (unsigned long long*)d_ws;
        unsigned int*       cnt = (unsigned int*)((char*)d_ws + 8);
        hipMemsetAsync(d_ws, 0, 64, stream);    // zero acc/cnt each call (capture-safe)
        crf_fused_kernel<<<B, 1024, 0, stream>>>(feats, Tm, tags, lengths,
                                                 acc, cnt, (float*)d_out, L);
    } else {
        double* partial = (double*)((char*)d_ws + 64);
        crf_fwd_kernel<<<B, 64, 0, stream>>>(feats, Tm, tags, lengths, partial, B, L);
        crf_reduce_kernel<<<1, 256, 0, stream>>>(partial, (float*)d_out, B);
    }
}